// Round 3
// baseline (407.791 us; speedup 1.0000x reference)
//
#include <hip/hip_runtime.h>

// Problem constants (match reference setup_inputs)
#define BB 16
#define TT 32641
#define EE 128
#define LL (TT + EE - 1)            // 32768 = 2^15 groups
#define NTH 256
#define GPB 256                     // groups per block (4 waves x 64 lanes)
#define BLK_X (LL / GPB)            // 128 blocks per batch
#define NBLK (BLK_X * BB)           // 2048 partials

// One kernel does everything:
//  lane owns group t; walks rows i in [t0w-127, t0w+63] reading x[i, t-i]
//  (consecutive lanes -> consecutive addresses -> coalesced dword loads).
//  Accumulates G = sum x, Q = sum x^2 in registers. Per-lane loss
//  contribution r = w*Q - (w*G)^2 with w = 1/c(t). Shuffle+LDS reduce,
//  one non-atomic float per block.
__global__ __launch_bounds__(NTH) void tc_fused(const float* __restrict__ in,
                                                float* __restrict__ part) {
    __shared__ float red[NTH / 64];
    const int tid  = threadIdx.x;
    const int lane = tid & 63;
    const int wv   = tid >> 6;
    const int b    = blockIdx.y;
    const int tw   = blockIdx.x * GPB + wv * 64;  // wave's first group
    const int t    = tw + lane;                   // this lane's group (< LL)

    const float w = 1.0f / (float)min(min(t + 1, EE), LL - t);

    const float* __restrict__ base = in + (size_t)b * TT * EE;
    const int ilo = max(0, tw - (EE - 1));        // wave-uniform bounds
    const int ihi = min(TT - 1, tw + 63);

    float G = 0.0f, Q = 0.0f;
    // element index for row i: i*EE + (t-i) = t + i*(EE-1)
    unsigned off = (unsigned)t + (unsigned)ilo * (EE - 1);
    #pragma unroll 8
    for (int i = ilo; i <= ihi; ++i) {
        unsigned c = (unsigned)(t - i);           // column; >=EE means masked
        if (c < (unsigned)EE) {
            float x = base[off];
            G += x;
            Q += x * x;
        }
        off += (EE - 1);
    }

    float r = w * Q - (w * G) * (w * G);
    #pragma unroll
    for (int o = 32; o > 0; o >>= 1) r += __shfl_down(r, o, 64);
    if (lane == 0) red[wv] = r;
    __syncthreads();
    if (tid == 0)
        part[blockIdx.y * gridDim.x + blockIdx.x] = red[0] + red[1] + red[2] + red[3];
}

__global__ __launch_bounds__(NTH) void tc_final(const float* __restrict__ part,
                                                float* __restrict__ out) {
    __shared__ float red[NTH / 64];
    float s = 0.0f;
    for (int i = threadIdx.x; i < NBLK; i += NTH) s += part[i];
    #pragma unroll
    for (int o = 32; o > 0; o >>= 1) s += __shfl_down(s, o, 64);
    if ((threadIdx.x & 63) == 0) red[threadIdx.x >> 6] = s;
    __syncthreads();
    if (threadIdx.x == 0) {
        const float scale = (float)(0.1 / ((double)BB * (double)LL));
        out[0] = (red[0] + red[1] + red[2] + red[3]) * scale;
    }
}

extern "C" void kernel_launch(void* const* d_in, const int* in_sizes, int n_in,
                              void* d_out, int out_size, void* d_ws, size_t ws_size,
                              hipStream_t stream) {
    const float* in = (const float*)d_in[0];
    float* part = (float*)d_ws;           // NBLK floats = 8 KB
    float* out  = (float*)d_out;

    dim3 g1(BLK_X, BB);
    tc_fused<<<g1, NTH, 0, stream>>>(in, part);
    tc_final<<<1, NTH, 0, stream>>>(part, out);
}

// Round 4
// 369.420 us; speedup vs baseline: 1.1039x; 1.1039x over previous
//
#include <hip/hip_runtime.h>

// Problem constants (match reference setup_inputs)
#define BB 16
#define TT 32641
#define EE 128
#define LL (TT + EE - 1)            // 32768 = 2^15 groups
#define NTH 256
#define GPB 256                     // groups per block (4 waves x 64 lanes)
#define BLK_X (LL / GPB)            // 128 blocks per batch
#define NBLK (BLK_X * BB)           // 2048 partials

// Lane owns group t. Walks rows i where x[i, t-i] exists; addresses for fixed i
// are consecutive across lanes (coalesced). Row walk split into:
//   prologue  i in [ilo, iF0)  : high lanes masked (col clamped to 127, weight 0)
//   full body i in [iF0, iF1]  : all 64 lanes valid -> branch-free 8-deep batches
//   epilogue  i in (iF1, ihi]  : low lanes masked (col clamped to 0, weight 0)
// Per-lane G = sum x, Q = sum x^2; contribution r = w*Q - (w*G)^2, w = 1/c(t).
__global__ __launch_bounds__(NTH) void tc_fused(const float* __restrict__ in,
                                                float* __restrict__ part) {
    __shared__ float red[NTH / 64];
    const int tid  = threadIdx.x;
    const int lane = tid & 63;
    const int wv   = tid >> 6;
    const int b    = blockIdx.y;
    const int tw   = blockIdx.x * GPB + wv * 64;  // wave's first group
    const int t    = tw + lane;                   // this lane's group

    const float w = 1.0f / (float)min(min(t + 1, EE), LL - t);
    const float* __restrict__ base = in + (size_t)b * TT * EE;

    const int ilo = max(0, tw - (EE - 1));
    const int ihi = min(TT - 1, tw + 63);
    const int iF0 = max(0, tw - 64);   // first fully-active row
    const int iF1 = min(TT - 1, tw);   // last fully-active row

    float G = 0.0f, Q = 0.0f;

    // ---- prologue: c = t - i in [1, 190]; clamp high, mask ----
    #pragma unroll 4
    for (int i = ilo; i < iF0; ++i) {
        int   c  = t - i;
        int   cc = min(c, EE - 1);
        float x  = base[(size_t)i * EE + cc];     // in-bounds always
        float m  = (c == cc) ? 1.0f : 0.0f;
        float xm = x * m;
        G += xm;
        Q += x * xm;
    }

    // ---- full body: unconditional, 8 loads in flight ----
    {
        // element (i, t-i) flat index = t + 127*i
        unsigned off = (unsigned)t + (unsigned)iF0 * (EE - 1);
        int n = iF1 - iF0 + 1;
        while (n >= 8) {
            float x0 = base[off + 0u * (EE - 1)];
            float x1 = base[off + 1u * (EE - 1)];
            float x2 = base[off + 2u * (EE - 1)];
            float x3 = base[off + 3u * (EE - 1)];
            float x4 = base[off + 4u * (EE - 1)];
            float x5 = base[off + 5u * (EE - 1)];
            float x6 = base[off + 6u * (EE - 1)];
            float x7 = base[off + 7u * (EE - 1)];
            G += x0 + x1 + x2 + x3 + x4 + x5 + x6 + x7;
            Q += x0 * x0; Q += x1 * x1; Q += x2 * x2; Q += x3 * x3;
            Q += x4 * x4; Q += x5 * x5; Q += x6 * x6; Q += x7 * x7;
            off += 8u * (EE - 1);
            n -= 8;
        }
        while (n > 0) {
            float x = base[off];
            G += x;
            Q += x * x;
            off += (EE - 1);
            --n;
        }
    }

    // ---- epilogue: c = t - i in [-63, 62]; clamp low, mask ----
    #pragma unroll 4
    for (int i = iF1 + 1; i <= ihi; ++i) {
        int   c  = t - i;
        int   cc = max(c, 0);
        float x  = base[(size_t)i * EE + cc];
        float m  = (c == cc) ? 1.0f : 0.0f;
        float xm = x * m;
        G += xm;
        Q += x * xm;
    }

    float r = w * Q - (w * G) * (w * G);
    #pragma unroll
    for (int o = 32; o > 0; o >>= 1) r += __shfl_down(r, o, 64);
    if (lane == 0) red[wv] = r;
    __syncthreads();
    if (tid == 0)
        part[blockIdx.y * gridDim.x + blockIdx.x] = red[0] + red[1] + red[2] + red[3];
}

__global__ __launch_bounds__(NTH) void tc_final(const float* __restrict__ part,
                                                float* __restrict__ out) {
    __shared__ float red[NTH / 64];
    float s = 0.0f;
    for (int i = threadIdx.x; i < NBLK; i += NTH) s += part[i];
    #pragma unroll
    for (int o = 32; o > 0; o >>= 1) s += __shfl_down(s, o, 64);
    if ((threadIdx.x & 63) == 0) red[threadIdx.x >> 6] = s;
    __syncthreads();
    if (threadIdx.x == 0) {
        const float scale = (float)(0.1 / ((double)BB * (double)LL));
        out[0] = (red[0] + red[1] + red[2] + red[3]) * scale;
    }
}

extern "C" void kernel_launch(void* const* d_in, const int* in_sizes, int n_in,
                              void* d_out, int out_size, void* d_ws, size_t ws_size,
                              hipStream_t stream) {
    const float* in = (const float*)d_in[0];
    float* part = (float*)d_ws;           // NBLK floats = 8 KB
    float* out  = (float*)d_out;

    dim3 g1(BLK_X, BB);
    tc_fused<<<g1, NTH, 0, stream>>>(in, part);
    tc_final<<<1, NTH, 0, stream>>>(part, out);
}

// Round 5
// 365.577 us; speedup vs baseline: 1.1155x; 1.0105x over previous
//
#include <hip/hip_runtime.h>

// Problem constants (match reference setup_inputs)
#define BB 16
#define TT 32641
#define EE 128
#define LL (TT + EE - 1)            // 32768 = 2^15 groups
#define NTH 256
#define GPB 256                     // groups per block (4 waves x 64 lanes)
#define BLK_X (LL / GPB)            // 128 blocks per batch
#define NBLK (BLK_X * BB)           // 2048 partials

// Lane owns group t = tw + lane. Element of group t in row i is x[i, t-i],
// flat index off = t + 127*i. Row start lo = 128*i. Clamped address
// a = lo + min(off-lo, 127) is always in [lo, lo+127] (in-bounds); the lane's
// element is valid exactly when a == off (verified for col<0 wrap, col>127,
// and padded-tail rows with the amax clamp). This makes EVERY row the same
// branch-free 8-deep batch: uniform MLP across the whole 160..191-row walk.
__global__ __launch_bounds__(NTH, 8) void tc_fused(const float* __restrict__ in,
                                                   float* __restrict__ part) {
    __shared__ float red[NTH / 64];
    const int tid  = threadIdx.x;
    const int lane = tid & 63;
    const int wv   = tid >> 6;
    const int b    = blockIdx.y;
    const int tw   = blockIdx.x * GPB + wv * 64;  // wave's first group
    const int t    = tw + lane;                   // this lane's group

    const float w = 1.0f / (float)min(min(t + 1, EE), LL - t);
    const float* __restrict__ base = in + (size_t)b * TT * EE;

    const int i0 = max(0, tw - (EE - 1));         // wave-uniform row range
    const int i1 = min(TT - 1, tw + 63);
    const int nrows = i1 - i0 + 1;                // 160..191

    float G = 0.0f, Q = 0.0f;

    unsigned off = (unsigned)t + (unsigned)i0 * (EE - 1);   // t + 127*i
    unsigned lo  = (unsigned)i0 * EE;                       // 128*i
    const unsigned amax = (unsigned)i1 * EE + (EE - 1);     // last valid flat idx

    // full batches: rows i0 .. i0+8*kb-1, all <= i1, no row clamp needed
    int kb = nrows >> 3;
    while (kb-- > 0) {
        #pragma unroll
        for (int s = 0; s < 8; ++s) {
            unsigned d  = off - lo;                      // column (wraps if <0)
            unsigned a  = lo + min(d, (unsigned)(EE - 1));
            float x = base[a];
            float m = (a == off) ? 1.0f : 0.0f;
            float xm = x * m;
            G += xm;
            Q += x * xm;
            off += (EE - 1);
            lo  += EE;
        }
    }
    // one padded batch of 8 covers the 0..7 remaining rows; rows beyond i1
    // are clamped to amax (in-bounds) and provably fail a == off.
    {
        #pragma unroll
        for (int s = 0; s < 8; ++s) {
            unsigned d  = off - lo;
            unsigned a  = min(lo + min(d, (unsigned)(EE - 1)), amax);
            float x = base[a];
            float m = (a == off) ? 1.0f : 0.0f;
            float xm = x * m;
            G += xm;
            Q += x * xm;
            off += (EE - 1);
            lo  += EE;
        }
    }

    float r = w * Q - (w * G) * (w * G);
    #pragma unroll
    for (int o = 32; o > 0; o >>= 1) r += __shfl_down(r, o, 64);
    if (lane == 0) red[wv] = r;
    __syncthreads();
    if (tid == 0)
        part[blockIdx.y * gridDim.x + blockIdx.x] = red[0] + red[1] + red[2] + red[3];
}

__global__ __launch_bounds__(NTH) void tc_final(const float* __restrict__ part,
                                                float* __restrict__ out) {
    __shared__ float red[NTH / 64];
    float s = 0.0f;
    for (int i = threadIdx.x; i < NBLK; i += NTH) s += part[i];
    #pragma unroll
    for (int o = 32; o > 0; o >>= 1) s += __shfl_down(s, o, 64);
    if ((threadIdx.x & 63) == 0) red[threadIdx.x >> 6] = s;
    __syncthreads();
    if (threadIdx.x == 0) {
        const float scale = (float)(0.1 / ((double)BB * (double)LL));
        out[0] = (red[0] + red[1] + red[2] + red[3]) * scale;
    }
}

extern "C" void kernel_launch(void* const* d_in, const int* in_sizes, int n_in,
                              void* d_out, int out_size, void* d_ws, size_t ws_size,
                              hipStream_t stream) {
    const float* in = (const float*)d_in[0];
    float* part = (float*)d_ws;           // NBLK floats = 8 KB
    float* out  = (float*)d_out;

    dim3 g1(BLK_X, BB);
    tc_fused<<<g1, NTH, 0, stream>>>(in, part);
    tc_final<<<1, NTH, 0, stream>>>(part, out);
}

// Round 7
// 351.374 us; speedup vs baseline: 1.1606x; 1.0404x over previous
//
#include <hip/hip_runtime.h>

// Problem constants (match reference setup_inputs)
#define BB 16
#define TT 32641
#define EE 128
#define LL (TT + EE - 1)             // 32768 = 2^15 groups
#define RT 64                        // rows per tile in pass 1
#define NT ((TT + RT - 1) / RT)      // 511 tiles per batch
#define GPT (RT + EE - 1)            // 191 group partials per tile
#define SLOT 192                     // stride: 191 G-partials + 1 Qw slot
#define NTH 256
#define P2_BLOCKS 256

typedef float vf4 __attribute__((ext_vector_type(4)));

// c(t) = |{(i,j): i+j==t, 0<=i<TT, 0<=j<EE}|  (TT >= EE)
__device__ __forceinline__ float groupWeight(int t) {
    int c = min(min(t + 1, EE), LL - t);
    return 1.0f / (float)c;
}

// Pass 1: one block per (tile, batch), REVERSED mapping so first-dispatched
// blocks read the most-recently-restored (L3-resident) end of the input.
//  Phase A: pure copy, 8 nontemporal float4 loads -> ds_write_b128 (MLP=8,
//           no VALU interleave, no L3 allocation on miss).
//  Phase B: thread d (<GPT) walks anti-diagonal d in LDS (conflict-free),
//           accumulating G = sum x AND q = sum x^2 (weight is constant along
//           a diagonal). Writes G partial; block-reduces w*q into slot GPT.
//  NOTE: qw only computed for NON-EMPTY diagonals — r0+d can exceed LL-1 on
//  the last tile where c(t)=0 -> w=inf -> 0*inf=NaN (the R6 bug).
__global__ __launch_bounds__(NTH) void tc_pass1(const float* __restrict__ in,
                                                float* __restrict__ part) {
    __shared__ float lsum[RT * EE];        // 32 KB
    __shared__ float red[NTH / 64];
    const int tid = threadIdx.x;
    const int k   = (NT - 1) - blockIdx.x;   // reversed tile order
    const int b   = (BB - 1) - blockIdx.y;   // reversed batch order
    const int r0  = k * RT;
    const int nrows = min(RT, TT - r0);

    const vf4* __restrict__ src = (const vf4*)(in + ((size_t)b * TT + r0) * EE);
    vf4* __restrict__ ldst = (vf4*)lsum;

    if (nrows == RT) {
        #pragma unroll
        for (int u = 0; u < RT * (EE / 4) / NTH; ++u) {   // 8 iterations
            int v = tid + u * NTH;
            ldst[v] = __builtin_nontemporal_load(&src[v]);
        }
    } else {
        const int nvec = nrows * (EE / 4);
        for (int v = tid; v < nvec; v += NTH)
            ldst[v] = __builtin_nontemporal_load(&src[v]);
    }
    __syncthreads();

    float* __restrict__ base = part + ((size_t)b * NT + k) * SLOT;

    // Phase B: lane d reads lsum[i*EE + (d-i)]; consecutive lanes ->
    // consecutive LDS addresses -> conflict-free.
    float qw = 0.0f;
    if (tid < GPT) {
        const int d = tid;
        const int ilo = max(0, d - (EE - 1));
        const int ihi = min(nrows - 1, d);
        float g = 0.0f, q = 0.0f;
        for (int i = ilo; i <= ihi; ++i) {
            float x = lsum[i * EE + (d - i)];
            g += x;
            q += x * x;
        }
        base[d] = g;                       // zero when loop empty
        if (ihi >= ilo) qw = q * groupWeight(r0 + d);   // guard: empty diag -> t may be >= LL
    }

    // block-reduce qw -> slot GPT (non-atomic)
    #pragma unroll
    for (int o = 32; o > 0; o >>= 1) qw += __shfl_down(qw, o, 64);
    if ((tid & 63) == 0) red[tid >> 6] = qw;
    __syncthreads();
    if (tid == 0) base[GPT] = red[0] + red[1] + red[2] + red[3];
}

// Pass 2: S1 = sum over (b,t) of (G(b,t)*w(t))^2 from <=3 tile partials;
//         S2 = sum of per-tile w*q slots. Non-atomic block partials.
__global__ __launch_bounds__(NTH) void tc_pass2(const float* __restrict__ part,
                                                float* __restrict__ part2) {
    __shared__ float redA[NTH / 64], redB[NTH / 64];
    float s1 = 0.0f, s2 = 0.0f;
    const int N = BB * LL;
    for (int idx = blockIdx.x * NTH + threadIdx.x; idx < N; idx += gridDim.x * NTH) {
        const int t  = idx & (LL - 1);
        const int b  = idx >> 15;              // LL = 2^15
        const int k0 = t >> 6;                 // RT = 64
        float g = 0.0f;
        #pragma unroll
        for (int dk = 2; dk >= 0; --dk) {
            const int k = k0 - dk;
            const int d = t - (k << 6);
            if (k >= 0 && k < NT && d >= 0 && d < GPT)
                g += part[((size_t)b * NT + k) * SLOT + d];
        }
        const float m = g * groupWeight(t);
        s1 += m * m;
    }
    const int NS = BB * NT;
    for (int idx = blockIdx.x * NTH + threadIdx.x; idx < NS; idx += gridDim.x * NTH) {
        s2 += part[(size_t)idx * SLOT + GPT];
    }
    #pragma unroll
    for (int o = 32; o > 0; o >>= 1) {
        s1 += __shfl_down(s1, o, 64);
        s2 += __shfl_down(s2, o, 64);
    }
    if ((threadIdx.x & 63) == 0) { redA[threadIdx.x >> 6] = s1; redB[threadIdx.x >> 6] = s2; }
    __syncthreads();
    if (threadIdx.x == 0) {
        part2[blockIdx.x * 2 + 0] = redA[0] + redA[1] + redA[2] + redA[3];
        part2[blockIdx.x * 2 + 1] = redB[0] + redB[1] + redB[2] + redB[3];
    }
}

__global__ __launch_bounds__(NTH) void tc_final(const float* __restrict__ part2,
                                                float* __restrict__ out) {
    __shared__ float redA[NTH / 64], redB[NTH / 64];
    float s1 = 0.0f, s2 = 0.0f;
    for (int i = threadIdx.x; i < P2_BLOCKS; i += NTH) {
        s1 += part2[i * 2 + 0];
        s2 += part2[i * 2 + 1];
    }
    #pragma unroll
    for (int o = 32; o > 0; o >>= 1) {
        s1 += __shfl_down(s1, o, 64);
        s2 += __shfl_down(s2, o, 64);
    }
    if ((threadIdx.x & 63) == 0) { redA[threadIdx.x >> 6] = s1; redB[threadIdx.x >> 6] = s2; }
    __syncthreads();
    if (threadIdx.x == 0) {
        const float scale = (float)(0.1 / ((double)BB * (double)LL));
        out[0] = (redB[0] + redB[1] + redB[2] + redB[3]
                - (redA[0] + redA[1] + redA[2] + redA[3])) * scale;
    }
}

extern "C" void kernel_launch(void* const* d_in, const int* in_sizes, int n_in,
                              void* d_out, int out_size, void* d_ws, size_t ws_size,
                              hipStream_t stream) {
    const float* in = (const float*)d_in[0];
    float* part  = (float*)d_ws;                          // BB*NT*SLOT floats ~ 6.3 MB
    float* part2 = part + (size_t)BB * NT * SLOT;         // P2_BLOCKS*2 floats
    float* out   = (float*)d_out;

    dim3 g1(NT, BB);
    tc_pass1<<<g1, NTH, 0, stream>>>(in, part);
    tc_pass2<<<P2_BLOCKS, NTH, 0, stream>>>(part, part2);
    tc_final<<<1, NTH, 0, stream>>>(part2, out);
}